// Round 1
// baseline (367.405 us; speedup 1.0000x reference)
//
#include <hip/hip_runtime.h>
#include <math.h>

#define NC   1000      // classes
#define DD   4096      // dense dim
#define BB   8192      // batch

// ws layout (bytes):
//     0: counts  int[1000]
//  4096: offsets int[1024]   (exclusive prefix of counts)
//  8192: cursor  int[1000]
// 12288: csr     int[8192]   (sample indices grouped by class)
// 45056: loss1   double
// 45064: loss2   double
#define WS_ZERO_BYTES 46080

__global__ void count_k(const int* __restrict__ target, int* __restrict__ counts) {
    int i = blockIdx.x * blockDim.x + threadIdx.x;
    if (i < BB) atomicAdd(&counts[target[i]], 1);
}

// single block, 1024 threads: exclusive scan over 1000 counts (padded)
__global__ void scan_k(const int* __restrict__ counts, int* __restrict__ offsets) {
    __shared__ int sh[1024];
    int t = threadIdx.x;
    int orig = (t < NC) ? counts[t] : 0;
    sh[t] = orig;
    __syncthreads();
    for (int off = 1; off < 1024; off <<= 1) {
        int v = (t >= off) ? sh[t - off] : 0;
        __syncthreads();
        sh[t] += v;
        __syncthreads();
    }
    offsets[t] = sh[t] - orig;   // exclusive
}

__global__ void scatter_k(const int* __restrict__ target,
                          const int* __restrict__ offsets,
                          int* __restrict__ cursor, int* __restrict__ csr) {
    int i = blockIdx.x * blockDim.x + threadIdx.x;
    if (i < BB) {
        int t = target[i];
        int pos = offsets[t] + atomicAdd(&cursor[t], 1);
        csr[pos] = i;
    }
}

// one wave (64 lanes) per sample: log_softmax row reduce + pick target logit
__global__ void ce_k(const float* __restrict__ logits,
                     const int* __restrict__ target,
                     double* __restrict__ loss1) {
    int i = blockIdx.x;
    int lane = threadIdx.x;
    const float* row = logits + (size_t)i * NC;
    float mx = -INFINITY;
    for (int j = lane; j < NC; j += 64) mx = fmaxf(mx, row[j]);
    for (int o = 32; o > 0; o >>= 1) mx = fmaxf(mx, __shfl_xor(mx, o));
    float s = 0.f;
    for (int j = lane; j < NC; j += 64) s += __expf(row[j] - mx);
    for (int o = 32; o > 0; o >>= 1) s += __shfl_xor(s, o);
    if (lane == 0) {
        float lp = row[target[i]] - mx - __logf(s);
        atomicAdd(loss1, (double)(-lp));
    }
}

// grid (1000 classes, 4 chunks of 1024 d's), 256 threads, 4 consecutive d / thread.
// Per block: y = dense_labels[c, d0:d0+1024] read once; loop over the class's
// samples (CSR), accumulate sigmoid into registers (no atomics) + BCE partial.
__global__ void main_k(const float* __restrict__ dense_out,
                       const float* __restrict__ dense_labels,
                       const int* __restrict__ counts,
                       const int* __restrict__ offsets,
                       const int* __restrict__ csr,
                       float* __restrict__ out_sum,   // d_out + 1 (4B-aligned only!)
                       double* __restrict__ loss2) {
    int c = blockIdx.x;
    int d = blockIdx.y * 1024 + threadIdx.x * 4;
    int n = counts[c];
    int o = offsets[c];

    float4 y = *(const float4*)(dense_labels + (size_t)c * DD + d);
    float a0 = 0.f, a1 = 0.f, a2 = 0.f, a3 = 0.f;
    float bce = 0.f;

    for (int s = 0; s < n; ++s) {
        int i = csr[o + s];
        float4 x = *(const float4*)(dense_out + (size_t)i * DD + d);
        {
            float e = __expf(-fabsf(x.x)); float inv = 1.f / (1.f + e);
            a0 += (x.x >= 0.f) ? inv : e * inv;
            bce += fmaxf(x.x, 0.f) - x.x * y.x + __logf(1.f + e);
        }
        {
            float e = __expf(-fabsf(x.y)); float inv = 1.f / (1.f + e);
            a1 += (x.y >= 0.f) ? inv : e * inv;
            bce += fmaxf(x.y, 0.f) - x.y * y.y + __logf(1.f + e);
        }
        {
            float e = __expf(-fabsf(x.z)); float inv = 1.f / (1.f + e);
            a2 += (x.z >= 0.f) ? inv : e * inv;
            bce += fmaxf(x.z, 0.f) - x.z * y.z + __logf(1.f + e);
        }
        {
            float e = __expf(-fabsf(x.w)); float inv = 1.f / (1.f + e);
            a3 += (x.w >= 0.f) ? inv : e * inv;
            bce += fmaxf(x.w, 0.f) - x.w * y.w + __logf(1.f + e);
        }
    }

    // out_sum base is d_out+1: only 4B-aligned -> scalar dword stores
    float* p = out_sum + (size_t)c * DD + d;
    p[0] = a0; p[1] = a1; p[2] = a2; p[3] = a3;

    // block-reduce bce -> one double atomic per block
    for (int o2 = 32; o2 > 0; o2 >>= 1) bce += __shfl_xor(bce, o2);
    __shared__ float wsum[4];
    int t = threadIdx.x;
    if ((t & 63) == 0) wsum[t >> 6] = bce;
    __syncthreads();
    if (t == 0) atomicAdd(loss2, (double)(wsum[0] + wsum[1] + wsum[2] + wsum[3]));
}

__global__ void fin_k(const int* __restrict__ counts,
                      const double* __restrict__ loss1,
                      const double* __restrict__ loss2,
                      float* __restrict__ out) {
    int t = blockIdx.x * blockDim.x + threadIdx.x;
    if (t < NC) out[1 + (size_t)NC * DD + t] = (float)counts[t];
    if (t == 0) {
        double l1 = *loss1 / (double)BB;
        double l2 = *loss2 / ((double)BB * (double)DD);
        out[0] = (float)(0.5 * l1 + 0.5 * l2);
    }
}

extern "C" void kernel_launch(void* const* d_in, const int* in_sizes, int n_in,
                              void* d_out, int out_size, void* d_ws, size_t ws_size,
                              hipStream_t stream) {
    const float* logits       = (const float*)d_in[0];
    const float* dense_out    = (const float*)d_in[1];
    const int*   target       = (const int*)d_in[2];
    const float* dense_labels = (const float*)d_in[3];
    float* out = (float*)d_out;

    char* ws = (char*)d_ws;
    int*    counts  = (int*)(ws + 0);
    int*    offsets = (int*)(ws + 4096);
    int*    cursor  = (int*)(ws + 8192);
    int*    csr     = (int*)(ws + 12288);
    double* loss1   = (double*)(ws + 45056);
    double* loss2   = (double*)(ws + 45064);

    hipMemsetAsync(d_ws, 0, WS_ZERO_BYTES, stream);

    count_k<<<BB / 256, 256, 0, stream>>>(target, counts);
    scan_k<<<1, 1024, 0, stream>>>(counts, offsets);
    scatter_k<<<BB / 256, 256, 0, stream>>>(target, offsets, cursor, csr);
    ce_k<<<BB, 64, 0, stream>>>(logits, target, loss1);

    dim3 grid(NC, DD / 1024);
    main_k<<<grid, 256, 0, stream>>>(dense_out, dense_labels, counts, offsets, csr,
                                     out + 1, loss2);
    fin_k<<<(NC + 255) / 256, 256, 0, stream>>>(counts, loss1, loss2, out);
}

// Round 2
// 286.925 us; speedup vs baseline: 1.2805x; 1.2805x over previous
//
#include <hip/hip_runtime.h>
#include <math.h>

#define NC   1000      // classes
#define DD   4096      // dense dim
#define BB   8192      // batch

// ws layout (bytes):
//    0: loss1 double
//    8: loss2 double
//   16: counts  int[1000]
// 4096: offsets int[1024]
// 8192: csr     int[8192]

// ---------------------------------------------------------------------------
// build_k: single block, 1024 threads. Count targets (LDS atomics), exclusive
// scan (Hillis-Steele in LDS), scatter sample ids into class-grouped CSR.
// ---------------------------------------------------------------------------
__global__ __launch_bounds__(1024) void build_k(const int* __restrict__ target,
                                                int* __restrict__ counts_g,
                                                int* __restrict__ offsets_g,
                                                int* __restrict__ csr) {
    __shared__ int scnt[1024];
    __shared__ int scur[1024];
    int t = threadIdx.x;
    scnt[t] = 0;
    __syncthreads();

    int tg[8];
    #pragma unroll
    for (int k = 0; k < 8; ++k) {
        tg[k] = target[k * 1024 + t];
        atomicAdd(&scnt[tg[k]], 1);
    }
    __syncthreads();

    int orig = scnt[t];
    __syncthreads();
    for (int off = 1; off < 1024; off <<= 1) {
        int v = (t >= off) ? scnt[t - off] : 0;
        __syncthreads();
        scnt[t] += v;
        __syncthreads();
    }
    int excl = scnt[t] - orig;           // exclusive prefix
    if (t < NC) { counts_g[t] = orig; offsets_g[t] = excl; }
    scur[t] = excl;
    __syncthreads();

    #pragma unroll
    for (int k = 0; k < 8; ++k) {
        int pos = atomicAdd(&scur[tg[k]], 1);
        csr[pos] = k * 1024 + t;
    }
}

// ---------------------------------------------------------------------------
// ce_k: 256 threads = 4 waves, one wave per sample. Row (1000 fp32) loaded
// once as 4 float4/lane (1024 slots; lanes with j0+768>=1000 use -inf, whose
// exp() is exactly 0). Single global pass, register-resident reduction.
// ---------------------------------------------------------------------------
__global__ __launch_bounds__(256) void ce_k(const float* __restrict__ logits,
                                            const int* __restrict__ target,
                                            double* __restrict__ loss1) {
    int wave = threadIdx.x >> 6;
    int lane = threadIdx.x & 63;
    int i = blockIdx.x * 4 + wave;
    const float* row = logits + (size_t)i * NC;
    int j0 = lane * 4;

    float4 r0 = *(const float4*)(row + j0);
    float4 r1 = *(const float4*)(row + j0 + 256);
    float4 r2 = *(const float4*)(row + j0 + 512);
    float4 r3;
    if (j0 + 768 < NC) r3 = *(const float4*)(row + j0 + 768);
    else r3 = make_float4(-INFINITY, -INFINITY, -INFINITY, -INFINITY);
    float tl = row[target[i]];   // all lanes same addr -> one transaction

    float mx = fmaxf(fmaxf(fmaxf(r0.x, r0.y), fmaxf(r0.z, r0.w)),
                     fmaxf(fmaxf(r1.x, r1.y), fmaxf(r1.z, r1.w)));
    mx = fmaxf(mx, fmaxf(fmaxf(r2.x, r2.y), fmaxf(r2.z, r2.w)));
    mx = fmaxf(mx, fmaxf(fmaxf(r3.x, r3.y), fmaxf(r3.z, r3.w)));
    #pragma unroll
    for (int o = 32; o > 0; o >>= 1) mx = fmaxf(mx, __shfl_xor(mx, o));

    float s = __expf(r0.x - mx) + __expf(r0.y - mx) + __expf(r0.z - mx) + __expf(r0.w - mx)
            + __expf(r1.x - mx) + __expf(r1.y - mx) + __expf(r1.z - mx) + __expf(r1.w - mx)
            + __expf(r2.x - mx) + __expf(r2.y - mx) + __expf(r2.z - mx) + __expf(r2.w - mx)
            + __expf(r3.x - mx) + __expf(r3.y - mx) + __expf(r3.z - mx) + __expf(r3.w - mx);
    #pragma unroll
    for (int o = 32; o > 0; o >>= 1) s += __shfl_xor(s, o);

    __shared__ float red[4];
    if (lane == 0) red[wave] = -(tl - mx - __logf(s));
    __syncthreads();
    if (threadIdx.x == 0)
        atomicAdd(loss1, (double)(red[0] + red[1] + red[2] + red[3]));
}

// ---------------------------------------------------------------------------
// main_k: grid (1000 classes, 4 chunks of 1024 d), 256 threads, 4 d/thread.
// Labels read once per block; class's sample ids staged in LDS; depth-2
// software pipeline on the dense_out float4 loads; register accumulation of
// the segment sum (no atomics) + BCE partial.
// ---------------------------------------------------------------------------
#define ACC1(xv, yv, acc)                                                     \
    {                                                                         \
        float e = __expf(-fabsf(xv));                                         \
        float inv = __builtin_amdgcn_rcpf(1.f + e);                           \
        acc += (xv >= 0.f) ? inv : e * inv;                                   \
        bce += fmaxf(xv, 0.f) - xv * yv + __logf(1.f + e);                    \
    }

__global__ __launch_bounds__(256) void main_k(const float* __restrict__ dense_out,
                                              const float* __restrict__ dense_labels,
                                              const int* __restrict__ counts,
                                              const int* __restrict__ offsets,
                                              const int* __restrict__ csr,
                                              float* __restrict__ out_sum,  // d_out+1
                                              double* __restrict__ loss2) {
    int c = blockIdx.x;
    int d = blockIdx.y * 1024 + (threadIdx.x << 2);
    int n = counts[c];
    int o = offsets[c];
    __shared__ int sidx[128];

    float4 y = *(const float4*)(dense_labels + (size_t)c * DD + d);
    float a0 = 0.f, a1 = 0.f, a2 = 0.f, a3 = 0.f, bce = 0.f;
    const float* dp = dense_out + d;

    for (int base = 0; base < n; base += 128) {
        int m = min(128, n - base);
        if (threadIdx.x < m) sidx[threadIdx.x] = csr[o + base + threadIdx.x];
        __syncthreads();

        float4 x0 = *(const float4*)(dp + (size_t)sidx[0] * DD);
        int s = 0;
        for (; s + 1 < m; ++s) {
            float4 x1 = *(const float4*)(dp + (size_t)sidx[s + 1] * DD);
            ACC1(x0.x, y.x, a0) ACC1(x0.y, y.y, a1)
            ACC1(x0.z, y.z, a2) ACC1(x0.w, y.w, a3)
            x0 = x1;
        }
        ACC1(x0.x, y.x, a0) ACC1(x0.y, y.y, a1)
        ACC1(x0.z, y.z, a2) ACC1(x0.w, y.w, a3)
        __syncthreads();
    }

    // out_sum base is d_out+1: only 4B-aligned -> scalar dword stores
    float* p = out_sum + (size_t)c * DD + d;
    p[0] = a0; p[1] = a1; p[2] = a2; p[3] = a3;

    #pragma unroll
    for (int o2 = 32; o2 > 0; o2 >>= 1) bce += __shfl_xor(bce, o2);
    __shared__ float wsum[4];
    int t = threadIdx.x;
    if ((t & 63) == 0) wsum[t >> 6] = bce;
    __syncthreads();
    if (t == 0) atomicAdd(loss2, (double)(wsum[0] + wsum[1] + wsum[2] + wsum[3]));
}

__global__ void fin_k(const int* __restrict__ counts,
                      const double* __restrict__ loss1,
                      const double* __restrict__ loss2,
                      float* __restrict__ out) {
    int t = blockIdx.x * blockDim.x + threadIdx.x;
    if (t < NC) out[1 + (size_t)NC * DD + t] = (float)counts[t];
    if (t == 0) {
        double l1 = *loss1 / (double)BB;
        double l2 = *loss2 / ((double)BB * (double)DD);
        out[0] = (float)(0.5 * l1 + 0.5 * l2);
    }
}

extern "C" void kernel_launch(void* const* d_in, const int* in_sizes, int n_in,
                              void* d_out, int out_size, void* d_ws, size_t ws_size,
                              hipStream_t stream) {
    const float* logits       = (const float*)d_in[0];
    const float* dense_out    = (const float*)d_in[1];
    const int*   target       = (const int*)d_in[2];
    const float* dense_labels = (const float*)d_in[3];
    float* out = (float*)d_out;

    char* ws = (char*)d_ws;
    double* loss1   = (double*)(ws + 0);
    double* loss2   = (double*)(ws + 8);
    int*    counts  = (int*)(ws + 16);
    int*    offsets = (int*)(ws + 4096);
    int*    csr     = (int*)(ws + 8192);

    hipMemsetAsync(d_ws, 0, 16, stream);   // just the two loss accumulators

    build_k<<<1, 1024, 0, stream>>>(target, counts, offsets, csr);
    ce_k<<<BB / 4, 256, 0, stream>>>(logits, target, loss1);

    dim3 grid(NC, DD / 1024);
    main_k<<<grid, 256, 0, stream>>>(dense_out, dense_labels, counts, offsets, csr,
                                     out + 1, loss2);
    fin_k<<<(NC + 255) / 256, 256, 0, stream>>>(counts, loss1, loss2, out);
}